// Round 1
// baseline (1120.857 us; speedup 1.0000x reference)
//
#include <hip/hip_runtime.h>
#include <math.h>

// SSM_18597208391915: HiPPO-LegT recurrence via O(N) semiseparable scans.
// h_{t+1} = tanh( M[(I + dt/2 A)h + dt*u*B] ),  M = (I - dt/2 A)^{-1}
// A = -(tril(P P^T) - diag(q)), P_n = sqrt(1+2n)  -> diag + rank-1 lower.
//   forward:  w_n = (1-(dt/2)(n+1)) h_n + (dt/2)P_n (2u - Sbar_n),
//             Sbar_n = sum_{k<n} P_k h_k                    (prefix sum)
//   solve:    y_n = (w_n - (dt/2)P_n Tbar_n) / d_n,  d_n = 1+(dt/2)(n+1)
//             Tbar_{n+1} = alpha_n Tbar_n + beta_n          (affine scan)
// One wave (64 lanes) per batch element; 16 state elems per lane; no grid
// sync needed (batch elements independent). fp64 accumulators, fp32 tanh.

#define SEQ     784
#define OUT_DIM 10
#define EPL     16   // elements per lane: 64*16 = 1024 = HIDDEN

__global__ __launch_bounds__(64, 1)
void ssm_hippo_scan(const float* __restrict__ x,     // (512, 784)
                    const float* __restrict__ C,     // (1024)
                    const float* __restrict__ W,     // (10)
                    const float* __restrict__ bvec,  // (10)
                    float* __restrict__ out)         // (512, 10)
{
    const int b    = blockIdx.x;
    const int lane = threadIdx.x & 63;

    __shared__ float u_s[SEQ];
    for (int t = lane; t < SEQ; t += 64) u_s[t] = x[b * SEQ + t];
    __syncthreads();

    const double dt  = 1.0 / (double)SEQ;
    const double hdt = 0.5 * dt;

    // per-element constants (n = lane*EPL + i), computed once in fp64
    double Pd[EPL], c1d[EPL], invdd[EPL], alphad[EPL];
#pragma unroll
    for (int i = 0; i < EPL; ++i) {
        const int    n = lane * EPL + i;
        const double p = sqrt(1.0 + 2.0 * (double)n);
        const double d = 1.0 + hdt * (double)(n + 1);
        Pd[i]     = p;
        c1d[i]    = 1.0 - hdt * (double)(n + 1);
        invdd[i]  = 1.0 / d;
        alphad[i] = 1.0 - hdt * p * p / d;
    }

    double h[EPL];
#pragma unroll
    for (int i = 0; i < EPL; ++i) h[i] = 0.0;

#pragma unroll 1
    for (int t = 0; t < SEQ; ++t) {
        const double u = (double)u_s[t];

        // ---- pass 1: strict local prefix of P*h (within-lane)
        double Sloc[EPL];
        double s = 0.0;
#pragma unroll
        for (int i = 0; i < EPL; ++i) { Sloc[i] = s; s = fma(Pd[i], h[i], s); }

        // cross-lane inclusive scan of lane totals
        double sc = s;
#pragma unroll
        for (int off = 1; off < 64; off <<= 1) {
            double v = __shfl_up(sc, off, 64);
            sc += (lane >= off) ? v : 0.0;
        }
        const double Sstart = sc - s;   // exclusive prefix across lanes

        // ---- w_n = c1*h + (dt/2)P*(2u - Sbar)
        double w[EPL];
#pragma unroll
        for (int i = 0; i < EPL; ++i) {
            const double Sn = Sloc[i] + Sstart;
            w[i] = fma(c1d[i], h[i], hdt * Pd[i] * (2.0 * u - Sn));
        }

        // ---- pass 2: local affine scan for Tbar (start 0), plus alpha products
        double Tloc[EPL], aprod[EPL];
        double Tl = 0.0, ap = 1.0;
#pragma unroll
        for (int i = 0; i < EPL; ++i) {
            Tloc[i]  = Tl;
            aprod[i] = ap;
            const double beta = Pd[i] * invdd[i] * w[i];   // off-chain
            Tl = fma(alphad[i], Tl, beta);
            ap *= alphad[i];
        }

        // cross-lane affine-map scan: (A,B) := cur ∘ incoming
        double A = ap, B = Tl;
#pragma unroll
        for (int off = 1; off < 64; off <<= 1) {
            double Ain = __shfl_up(A, off, 64);
            double Bin = __shfl_up(B, off, 64);
            Ain = (lane >= off) ? Ain : 1.0;
            Bin = (lane >= off) ? Bin : 0.0;
            B = fma(A, Bin, B);   // B before A update!
            A *= Ain;
        }
        double Tstart = __shfl_up(B, 1, 64);  // exclusive: map of lanes < L applied to 0
        if (lane == 0) Tstart = 0.0;

        // ---- apply solve + tanh
#pragma unroll
        for (int i = 0; i < EPL; ++i) {
            const double Tn = fma(aprod[i], Tstart, Tloc[i]);
            const double y  = (w[i] - hdt * Pd[i] * Tn) * invdd[i];
            const float yf  = (float)y;
            const float a   = fabsf(yf);
            const float e2  = __expf(-2.0f * a);                       // exp(-2|y|) in (0,1]
            const float th  = (1.0f - e2) * __builtin_amdgcn_rcpf(1.0f + e2);
            h[i] = (double)copysignf(th, yf);
        }
    }

    // ---- epilogue: yb = dot(h, C);  out[b,o] = yb*W[o] + bias[o]
    double acc = 0.0;
#pragma unroll
    for (int i = 0; i < EPL; ++i)
        acc = fma((double)C[lane * EPL + i], h[i], acc);
#pragma unroll
    for (int off = 32; off > 0; off >>= 1)
        acc += __shfl_down(acc, off, 64);
    const double tot = __shfl(acc, 0, 64);
    if (lane < OUT_DIM)
        out[b * OUT_DIM + lane] = (float)fma(tot, (double)W[lane], (double)bvec[lane]);
}

extern "C" void kernel_launch(void* const* d_in, const int* in_sizes, int n_in,
                              void* d_out, int out_size, void* d_ws, size_t ws_size,
                              hipStream_t stream) {
    const float* x  = (const float*)d_in[0];   // (512, 784, 1)
    const float* C  = (const float*)d_in[1];   // (1, 1024)
    const float* W  = (const float*)d_in[2];   // (1, 10)
    const float* bv = (const float*)d_in[3];   // (10,)
    float* out      = (float*)d_out;           // (512, 10)
    hipLaunchKernelGGL(ssm_hippo_scan, dim3(512), dim3(64), 0, stream,
                       x, C, W, bv, out);
}

// Round 3
// 513.560 us; speedup vs baseline: 2.1825x; 2.1825x over previous
//
#include <hip/hip_runtime.h>
#include <math.h>

// SSM_18597208391915: HiPPO-LegT recurrence via O(N) semiseparable scans.
// h_{t+1} = tanh( M[(I + dt/2 A)h + dt*u*B] ),  M = (I - dt/2 A)^{-1}
// A = -(tril(P P^T) - diag(q)), P_n = sqrt(1+2n)  -> diag + rank-1 lower.
//   forward:  w_n = (1-(dt/2)(n+1)) h_n + (dt/2)P_n (2u - Sbar_n),
//             Sbar_n = sum_{k<n} P_k h_k                    (prefix sum)
//   solve:    y_n = (w_n - (dt/2)P_n Tbar_n) / d_n,  d_n = 1+(dt/2)(n+1)
//             Tbar_{n+1} = alpha_n Tbar_n + (P_n/d_n) w_n   (affine scan)
// One wave per batch element. R1/R2: DPP wave scans (row_shr/row_bcast for
// the inclusive scans, wave_shr:1 for the exclusive shift — gfx9-lineage DPP
// ctrl 0x138, valid on gfx950) replace ds_bpermute __shfl; fp32 step loop.

#define SEQ     784
#define OUT_DIM 10
#define EPL     16   // elements per lane: 64*16 = 1024 = HIDDEN

// DPP move: result = src shuffled per CTRL; invalid/masked lanes get `old`.
template<int CTRL, int ROW_MASK>
__device__ __forceinline__ float dpp_mov(float src, float old) {
    return __int_as_float(__builtin_amdgcn_update_dpp(
        __float_as_int(old), __float_as_int(src), CTRL, ROW_MASK, 0xf, false));
}
// DPP ctrls: row_shr:N = 0x110|N, row_bcast15 = 0x142, row_bcast31 = 0x143,
//            wave_shr:1 = 0x138 (whole-wave shift down one lane, gfx9/CDNA)

// inclusive 64-lane sum scan, 6 VALU-latency levels (no LDS)
__device__ __forceinline__ float wave_incl_sum(float x) {
    x += dpp_mov<0x111, 0xf>(x, 0.0f);   // + lane-1 (within row16)
    x += dpp_mov<0x112, 0xf>(x, 0.0f);   // + lane-2
    x += dpp_mov<0x114, 0xf>(x, 0.0f);   // + lane-4
    x += dpp_mov<0x118, 0xf>(x, 0.0f);   // + lane-8   -> within-row inclusive
    x += dpp_mov<0x142, 0xa>(x, 0.0f);   // rows 1,3 += lane15/47 (prev row total)
    x += dpp_mov<0x143, 0xc>(x, 0.0f);   // rows 2,3 += lane31 ([0..31] total)
    return x;
}

__global__ __launch_bounds__(64, 1)
void ssm_hippo_scan(const float* __restrict__ x,     // (512, 784)
                    const float* __restrict__ C,     // (1024)
                    const float* __restrict__ W,     // (10)
                    const float* __restrict__ bvec,  // (10)
                    float* __restrict__ out)         // (512, 10)
{
    const int b    = blockIdx.x;
    const int lane = threadIdx.x & 63;

    __shared__ float u_s[SEQ];
    for (int t = lane; t < SEQ; t += 64) u_s[t] = x[b * SEQ + t];
    __syncthreads();

    const double dt  = 1.0 / (double)SEQ;
    const double hdt = 0.5 * dt;

    // per-element constants (n = lane*EPL + i): derive in fp64, hold in fp32
    float Pf[EPL], c1f[EPL], invdf[EPL], alphaf[EPL], hpf[EPL], pdinf[EPL];
#pragma unroll
    for (int i = 0; i < EPL; ++i) {
        const int    n = lane * EPL + i;
        const double p = sqrt(1.0 + 2.0 * (double)n);
        const double d = 1.0 + hdt * (double)(n + 1);
        Pf[i]     = (float)p;
        c1f[i]    = (float)(1.0 - hdt * (double)(n + 1));
        invdf[i]  = (float)(1.0 / d);
        alphaf[i] = (float)(1.0 - hdt * p * p / d);
        hpf[i]    = (float)(hdt * p);
        pdinf[i]  = (float)(p / d);
    }

    float h[EPL];
#pragma unroll
    for (int i = 0; i < EPL; ++i) h[i] = 0.0f;

#pragma unroll 1
    for (int t = 0; t < SEQ; ++t) {
        const float u2 = 2.0f * u_s[t];

        // ---- pass 1: strict local prefix of P*h, then DPP wave scan
        float Sloc[EPL];
        float s = 0.0f;
#pragma unroll
        for (int i = 0; i < EPL; ++i) { Sloc[i] = s; s = fmaf(Pf[i], h[i], s); }
        const float sc     = wave_incl_sum(s);
        const float Sstart = sc - s;             // exclusive prefix across lanes

        // ---- w_n = c1*h + (dt/2)P*(2u - Sbar); local affine scan for Tbar
        float w[EPL], Tloc[EPL], aprod[EPL];
        float Tl = 0.0f, ap = 1.0f;
#pragma unroll
        for (int i = 0; i < EPL; ++i) {
            const float Sn = Sstart + Sloc[i];
            const float wv = fmaf(c1f[i], h[i], hpf[i] * (u2 - Sn));
            w[i]     = wv;
            Tloc[i]  = Tl;
            aprod[i] = ap;
            Tl = fmaf(alphaf[i], Tl, pdinf[i] * wv);
            ap *= alphaf[i];
        }

        // ---- cross-lane affine-map scan via DPP: map = (A,B), new = cur∘in
        float A = ap, B = Tl;
#define AFF_LEVEL(CTRL, MASK)                          \
        {                                              \
            float Ain = dpp_mov<CTRL, MASK>(A, 1.0f);  \
            float Bin = dpp_mov<CTRL, MASK>(B, 0.0f);  \
            B = fmaf(A, Bin, B);  /* B before A! */    \
            A *= Ain;                                  \
        }
        AFF_LEVEL(0x111, 0xf)
        AFF_LEVEL(0x112, 0xf)
        AFF_LEVEL(0x114, 0xf)
        AFF_LEVEL(0x118, 0xf)
        AFF_LEVEL(0x142, 0xa)
        AFF_LEVEL(0x143, 0xc)
#undef AFF_LEVEL

        // exclusive B: whole-wave shift down one lane; lane0 gets 0.
        const float Tstart = dpp_mov<0x138, 0xf>(B, 0.0f);   // wave_shr:1

        // ---- apply solve + tanh (fp32)
#pragma unroll
        for (int i = 0; i < EPL; ++i) {
            const float Tn = fmaf(aprod[i], Tstart, Tloc[i]);
            const float y  = fmaf(-hpf[i], Tn, w[i]) * invdf[i];
            const float a  = fabsf(y);
            const float e2 = __expf(-2.0f * a);
            const float th = (1.0f - e2) * __builtin_amdgcn_rcpf(1.0f + e2);
            h[i] = copysignf(th, y);
        }
    }

    // ---- epilogue (once): yb = dot(h, C);  out[b,o] = yb*W[o] + bias[o]
    double acc = 0.0;
#pragma unroll
    for (int i = 0; i < EPL; ++i)
        acc = fma((double)C[lane * EPL + i], (double)h[i], acc);
#pragma unroll
    for (int off = 32; off > 0; off >>= 1)
        acc += __shfl_down(acc, off, 64);
    const double tot = __shfl(acc, 0, 64);
    if (lane < OUT_DIM)
        out[b * OUT_DIM + lane] = (float)fma(tot, (double)W[lane], (double)bvec[lane]);
}

extern "C" void kernel_launch(void* const* d_in, const int* in_sizes, int n_in,
                              void* d_out, int out_size, void* d_ws, size_t ws_size,
                              hipStream_t stream) {
    const float* x  = (const float*)d_in[0];   // (512, 784, 1)
    const float* C  = (const float*)d_in[1];   // (1, 1024)
    const float* W  = (const float*)d_in[2];   // (1, 10)
    const float* bv = (const float*)d_in[3];   // (10,)
    float* out      = (float*)d_out;           // (512, 10)
    hipLaunchKernelGGL(ssm_hippo_scan, dim3(512), dim3(64), 0, stream,
                       x, C, W, bv, out);
}

// Round 4
// 437.302 us; speedup vs baseline: 2.5631x; 1.1744x over previous
//
#include <hip/hip_runtime.h>
#include <math.h>

// SSM_18597208391915: HiPPO-LegT recurrence, O(N) via semiseparable solve.
// KEY ALGEBRA (R4): Ad = (I-cA)^{-1}(I+cA) = 2M - I  (c = dt/2, M=(I-cA)^{-1})
//   => h' = tanh(2*M(h + c*u*P) - h)   -- the forward (I+cA) pass and its
//   prefix-sum scan are GONE; only the M-solve affine scan remains.
// Solve (I-cA) y = w  (A = -(tril(PP^T)-diag(q)), P_n=sqrt(1+2n)):
//   y_n = (w_n - c P_n T_n)/d_n,  d_n = 1+c(n+1),
//   T_{n+1} = alpha_n T_n + (P_n/d_n) w_n,  alpha_n = 1 - c P_n^2/d_n.
// One wave per batch element (512 blocks x 64 lanes, 16 elems/lane).
// The affine-scan A-side is data-independent: per-lane alpha products and
// the 6 DPP-level A values are precomputed once; per step only the B chain
// (6 dpp + 6 fma) runs. tanh(g) = 1 - 2/(exp(2g)+1): no abs/copysign needed
// (fp32 inf/0 saturate to +-1 correctly).

#define SEQ     784
#define OUT_DIM 10
#define EPL     16   // elements per lane: 64*16 = 1024 = HIDDEN

// DPP move: result = src shuffled per CTRL; invalid/masked lanes get `old`.
template<int CTRL, int ROW_MASK>
__device__ __forceinline__ float dpp_mov(float src, float old) {
    return __int_as_float(__builtin_amdgcn_update_dpp(
        __float_as_int(old), __float_as_int(src), CTRL, ROW_MASK, 0xf, false));
}
// DPP ctrls: row_shr:N = 0x110|N, row_bcast15 = 0x142, row_bcast31 = 0x143,
//            wave_shr:1 = 0x138 (whole-wave shift down one lane, gfx9/CDNA)

__global__ __launch_bounds__(64, 1)
void ssm_hippo_scan(const float* __restrict__ x,     // (512, 784)
                    const float* __restrict__ C,     // (1024)
                    const float* __restrict__ W,     // (10)
                    const float* __restrict__ bvec,  // (10)
                    float* __restrict__ out)         // (512, 10)
{
    const int b    = blockIdx.x;
    const int lane = threadIdx.x & 63;

    __shared__ float u_s[SEQ + 1];
    for (int t = lane; t < SEQ; t += 64) u_s[t] = x[b * SEQ + t];
    if (lane == 0) u_s[SEQ] = 0.0f;
    __syncthreads();

    const double hdt = 0.5 / (double)SEQ;   // c = dt/2

    // per-element constants (n = lane*EPL + i): derive in fp64, hold in fp32
    float hdtP[EPL], alphaf[EPL], pdinf[EPL], invd2f[EPL], aprodf[EPL];
    float Alev0, Alev1, Alev2, Alev3, Alev4, Alev5;
    {
        float ap = 1.0f;
#pragma unroll
        for (int i = 0; i < EPL; ++i) {
            const int    n = lane * EPL + i;
            const double p = sqrt(1.0 + 2.0 * (double)n);
            const double d = 1.0 + hdt * (double)(n + 1);
            hdtP[i]   = (float)(hdt * p);
            alphaf[i] = (float)(1.0 - hdt * p * p / d);
            pdinf[i]  = (float)(p / d);
            invd2f[i] = (float)(2.0 / d);
            aprodf[i] = ap;                 // prod of alphas j<i (this lane)
            ap *= alphaf[i];
        }
        // ap = full per-lane alpha product (the scan map's A component).
        // Precompute the A value entering each of the 6 DPP scan levels.
        float A = ap;
        Alev0 = A; A *= dpp_mov<0x111, 0xf>(A, 1.0f);
        Alev1 = A; A *= dpp_mov<0x112, 0xf>(A, 1.0f);
        Alev2 = A; A *= dpp_mov<0x114, 0xf>(A, 1.0f);
        Alev3 = A; A *= dpp_mov<0x118, 0xf>(A, 1.0f);
        Alev4 = A; A *= dpp_mov<0x142, 0xa>(A, 1.0f);
        Alev5 = A;
    }

    float h[EPL];
#pragma unroll
    for (int i = 0; i < EPL; ++i) h[i] = 0.0f;

    float u = u_s[0];
#pragma unroll 1
    for (int t = 0; t < SEQ; ++t) {
        const float u_nx = u_s[t + 1];     // prefetch (latency hidden)

        // ---- w = h + c*u*P (elementwise);  local affine scan for T
        float w[EPL], Tloc[EPL];
        float Tl = 0.0f;
#pragma unroll
        for (int i = 0; i < EPL; ++i) {
            const float wv = fmaf(hdtP[i], u, h[i]);
            w[i]    = wv;
            Tloc[i] = Tl;
            Tl = fmaf(alphaf[i], Tl, pdinf[i] * wv);
        }

        // ---- cross-lane affine scan, B chain only (A precomputed)
        float B = Tl;
        {
            float Bin;
            Bin = dpp_mov<0x111, 0xf>(B, 0.0f); B = fmaf(Alev0, Bin, B);
            Bin = dpp_mov<0x112, 0xf>(B, 0.0f); B = fmaf(Alev1, Bin, B);
            Bin = dpp_mov<0x114, 0xf>(B, 0.0f); B = fmaf(Alev2, Bin, B);
            Bin = dpp_mov<0x118, 0xf>(B, 0.0f); B = fmaf(Alev3, Bin, B);
            Bin = dpp_mov<0x142, 0xa>(B, 0.0f); B = fmaf(Alev4, Bin, B);
            Bin = dpp_mov<0x143, 0xc>(B, 0.0f); B = fmaf(Alev5, Bin, B);
        }
        // exclusive: whole-wave shift down one lane; lane0 gets 0.
        const float Tstart = dpp_mov<0x138, 0xf>(B, 0.0f);

        // ---- apply solve + h' = tanh(2*y - h)
#pragma unroll
        for (int i = 0; i < EPL; ++i) {
            const float Tn  = fmaf(aprodf[i], Tstart, Tloc[i]);
            const float tmp = fmaf(-hdtP[i], Tn, w[i]);    // w - cP*T
            const float g   = fmaf(tmp, invd2f[i], -h[i]); // 2*tmp/d - h
            const float e   = __expf(2.0f * g);
            const float r   = __builtin_amdgcn_rcpf(e + 1.0f);
            h[i] = fmaf(-2.0f, r, 1.0f);                   // tanh(g)
        }
        u = u_nx;
    }

    // ---- epilogue (once): yb = dot(h, C);  out[b,o] = yb*W[o] + bias[o]
    double acc = 0.0;
#pragma unroll
    for (int i = 0; i < EPL; ++i)
        acc = fma((double)C[lane * EPL + i], (double)h[i], acc);
#pragma unroll
    for (int off = 32; off > 0; off >>= 1)
        acc += __shfl_down(acc, off, 64);
    const double tot = __shfl(acc, 0, 64);
    if (lane < OUT_DIM)
        out[b * OUT_DIM + lane] = (float)fma(tot, (double)W[lane], (double)bvec[lane]);
}

extern "C" void kernel_launch(void* const* d_in, const int* in_sizes, int n_in,
                              void* d_out, int out_size, void* d_ws, size_t ws_size,
                              hipStream_t stream) {
    const float* x  = (const float*)d_in[0];   // (512, 784, 1)
    const float* C  = (const float*)d_in[1];   // (1, 1024)
    const float* W  = (const float*)d_in[2];   // (1, 10)
    const float* bv = (const float*)d_in[3];   // (10,)
    float* out      = (float*)d_out;           // (512, 10)
    hipLaunchKernelGGL(ssm_hippo_scan, dim3(512), dim3(64), 0, stream,
                       x, C, W, bv, out);
}

// Round 5
// 359.245 us; speedup vs baseline: 3.1200x; 1.2173x over previous
//
#include <hip/hip_runtime.h>
#include <math.h>

// SSM_18597208391915: HiPPO-LegT recurrence, O(N) via semiseparable solve.
// Ad = (I-cA)^{-1}(I+cA) = 2M - I  =>  h' = tanh(2*M(h + c*u*P) - h).
// Solve (I-cA) y = w:  y_n = (w_n - c P_n T_n)/d_n,
//   T_{n+1} = alpha_n T_n + (P_n/d_n) w_n,  alpha_n = 1 - c P_n^2/d_n.
// One wave per batch element; wall time = single-wave latency x 784 steps
// (occupancy irrelevant - all 512 waves independent & co-resident).
// R5: (a) packed fp32 (v_pk_fma_f32) via ext_vector float2 for all
// elementwise math; (b) state scaled Hs = 2*log2e*h so tanh needs only
// exp2 + rcp + 1 pk_fma (no multiplies); (c) local affine scan split into
// two 8-deep chains + compose (hi-half fixup overlaps the DPP-chain wait).
// Cross-lane affine scan: DPP B-chain with data-independent A precomputed.

#define SEQ     784
#define OUT_DIM 10
#define EPL     16   // elements per lane: 64*16 = 1024 = HIDDEN

typedef float v2f __attribute__((ext_vector_type(2)));

#if __has_builtin(__builtin_elementwise_fma)
__device__ __forceinline__ v2f fma2(v2f a, v2f b, v2f c) {
    return __builtin_elementwise_fma(a, b, c);
}
#else
__device__ __forceinline__ v2f fma2(v2f a, v2f b, v2f c) {
    v2f r; r.x = fmaf(a.x, b.x, c.x); r.y = fmaf(a.y, b.y, c.y); return r;
}
#endif

#if __has_builtin(__builtin_amdgcn_exp2f)
#define EXP2F(x) __builtin_amdgcn_exp2f(x)
#else
#define EXP2F(x) __expf(0.69314718055994531f * (x))
#endif

// DPP move: result = src shuffled per CTRL; invalid/masked lanes get `old`.
template<int CTRL, int ROW_MASK>
__device__ __forceinline__ float dpp_mov(float src, float old) {
    return __int_as_float(__builtin_amdgcn_update_dpp(
        __float_as_int(old), __float_as_int(src), CTRL, ROW_MASK, 0xf, false));
}
// DPP ctrls: row_shr:N = 0x110|N, row_bcast15 = 0x142, row_bcast31 = 0x143,
//            wave_shr:1 = 0x138 (whole-wave shift down one lane)

__global__ __launch_bounds__(64, 1)
void ssm_hippo_scan(const float* __restrict__ x,     // (512, 784)
                    const float* __restrict__ C,     // (1024)
                    const float* __restrict__ W,     // (10)
                    const float* __restrict__ bvec,  // (10)
                    float* __restrict__ out)         // (512, 10)
{
    const int b    = blockIdx.x;
    const int lane = threadIdx.x & 63;

    __shared__ float u_s[SEQ + 1];
    for (int t = lane; t < SEQ; t += 64) u_s[t] = x[b * SEQ + t];
    if (lane == 0) u_s[SEQ] = 0.0f;
    __syncthreads();

    const double hdt   = 0.5 / (double)SEQ;            // c = dt/2
    const double L2E2  = 2.0 * 1.4426950408889634;     // 2*log2(e)

    // ---- per-element constants (n = lane*EPL + i), derived in fp64
    v2f  upc2[EPL/2];    // 2*log2e * c * P      (drives w in scaled space)
    v2f  nhdtP2[EPL/2];  // -c*P
    v2f  pdin2[EPL/2];   // P/d
    v2f  invd2v[EPL/2];  // 2/d
    v2f  aprod2[EPL/2];  // prod_{j<i} alpha_j (within lane)
    v2f  aprel2[4];      // i>=8: aprod[i]/aprod[8]
    float alphas[EPL];
    float apH;           // prod alpha_{8..15}
    float Alev0, Alev1, Alev2, Alev3, Alev4, Alev5;
    {
        double apd = 1.0, ap8 = 1.0;
        double aprd[EPL];
#pragma unroll
        for (int i = 0; i < EPL; ++i) {
            const int    n = lane * EPL + i;
            const double p = sqrt(1.0 + 2.0 * (double)n);
            const double d = 1.0 + hdt * (double)(n + 1);
            const double a = 1.0 - hdt * p * p / d;
            upc2[i>>1][i&1]   = (float)(L2E2 * hdt * p);
            nhdtP2[i>>1][i&1] = (float)(-hdt * p);
            pdin2[i>>1][i&1]  = (float)(p / d);
            invd2v[i>>1][i&1] = (float)(2.0 / d);
            alphas[i]         = (float)a;
            aprd[i] = apd;
            aprod2[i>>1][i&1] = (float)apd;
            apd *= a;
            if (i == 8) ap8 = aprd[8];
        }
        apH = (float)(apd / ap8);
#pragma unroll
        for (int i = 8; i < EPL; ++i)
            aprel2[(i-8)>>1][i&1] = (float)(aprd[i] / ap8);
        // full-lane alpha product -> precompute DPP-level A values
        float A = (float)apd;
        Alev0 = A; A *= dpp_mov<0x111, 0xf>(A, 1.0f);
        Alev1 = A; A *= dpp_mov<0x112, 0xf>(A, 1.0f);
        Alev2 = A; A *= dpp_mov<0x114, 0xf>(A, 1.0f);
        Alev3 = A; A *= dpp_mov<0x118, 0xf>(A, 1.0f);
        Alev4 = A; A *= dpp_mov<0x142, 0xa>(A, 1.0f);
        Alev5 = A;
    }

    const float c2  = (float)L2E2;          //  2*log2e
    const float nc4 = (float)(-2.0 * L2E2); // -4*log2e

    // state Hs = 2*log2e * h
    v2f h2[EPL/2];
#pragma unroll
    for (int j = 0; j < EPL/2; ++j) h2[j] = (v2f){0.0f, 0.0f};

    float u = u_s[0];
#pragma unroll 1
    for (int t = 0; t < SEQ; ++t) {
        const float u_nx = u_s[t + 1];     // prefetch (latency hidden)

        // ---- W = Hs + (2 log2e c P) u ; gamma = (P/d) W   (all packed)
        v2f wv2[EPL/2], gam2[EPL/2], Tb2[EPL/2];
        const v2f uu = (v2f){u, u};
#pragma unroll
        for (int j = 0; j < EPL/2; ++j) {
            wv2[j]  = fma2(upc2[j], uu, h2[j]);
            gam2[j] = pdin2[j] * wv2[j];
        }

        // ---- local affine scan, two 8-deep chains (alpha const, gamma data)
        float Tl0 = 0.0f, Tl1 = 0.0f;
#pragma unroll
        for (int i = 0; i < 8; ++i) {
            Tb2[i>>1][i&1] = Tl0;
            Tl0 = fmaf(alphas[i], Tl0, gam2[i>>1][i&1]);
        }
#pragma unroll
        for (int i = 8; i < EPL; ++i) {
            Tb2[i>>1][i&1] = Tl1;
            Tl1 = fmaf(alphas[i], Tl1, gam2[i>>1][i&1]);
        }
        const float Tl = fmaf(apH, Tl0, Tl1);   // lane total (affine B)

        // ---- cross-lane affine scan, B chain only (A precomputed)
        float B = Tl;
        float Bin;
        Bin = dpp_mov<0x111, 0xf>(B, 0.0f); B = fmaf(Alev0, Bin, B);
        Bin = dpp_mov<0x112, 0xf>(B, 0.0f); B = fmaf(Alev1, Bin, B);
        // hi-half fixup overlaps the DPP-chain latency:
        const v2f T8 = (v2f){Tl0, Tl0};
        Tb2[4] = fma2(aprel2[0], T8, Tb2[4]);
        Tb2[5] = fma2(aprel2[1], T8, Tb2[5]);
        Tb2[6] = fma2(aprel2[2], T8, Tb2[6]);
        Tb2[7] = fma2(aprel2[3], T8, Tb2[7]);
        Bin = dpp_mov<0x114, 0xf>(B, 0.0f); B = fmaf(Alev2, Bin, B);
        Bin = dpp_mov<0x118, 0xf>(B, 0.0f); B = fmaf(Alev3, Bin, B);
        Bin = dpp_mov<0x142, 0xa>(B, 0.0f); B = fmaf(Alev4, Bin, B);
        Bin = dpp_mov<0x143, 0xc>(B, 0.0f); B = fmaf(Alev5, Bin, B);
        // exclusive: whole-wave shift down one lane; lane0 gets 0.
        const float Tstart = dpp_mov<0x138, 0xf>(B, 0.0f);
        const v2f Tst = (v2f){Tstart, Tstart};

        // ---- apply solve + Hs' = 2 log2e * tanh(g), g2l = log2e*2g
#pragma unroll
        for (int j = 0; j < EPL/2; ++j) {
            const v2f Tn  = fma2(aprod2[j], Tst, Tb2[j]);
            const v2f tmp = fma2(nhdtP2[j], Tn, wv2[j]);
            const v2f g2l = fma2(tmp, invd2v[j], -h2[j]);
            v2f e;
            e.x = EXP2F(g2l.x);
            e.y = EXP2F(g2l.y);
            const v2f ep = e + (v2f){1.0f, 1.0f};
            v2f r;
            r.x = __builtin_amdgcn_rcpf(ep.x);
            r.y = __builtin_amdgcn_rcpf(ep.y);
            h2[j] = fma2((v2f){nc4, nc4}, r, (v2f){c2, c2});
        }
        u = u_nx;
    }

    // ---- epilogue (once): h = Hs/(2 log2e); out[b,o] = dot(h,C)*W[o]+b[o]
    double acc = 0.0;
#pragma unroll
    for (int i = 0; i < EPL; ++i)
        acc = fma((double)C[lane * EPL + i], (double)h2[i>>1][i&1], acc);
#pragma unroll
    for (int off = 32; off > 0; off >>= 1)
        acc += __shfl_down(acc, off, 64);
    const double tot = __shfl(acc, 0, 64) / (2.0 * 1.4426950408889634);
    if (lane < OUT_DIM)
        out[b * OUT_DIM + lane] = (float)fma(tot, (double)W[lane], (double)bvec[lane]);
}

extern "C" void kernel_launch(void* const* d_in, const int* in_sizes, int n_in,
                              void* d_out, int out_size, void* d_ws, size_t ws_size,
                              hipStream_t stream) {
    const float* x  = (const float*)d_in[0];   // (512, 784, 1)
    const float* C  = (const float*)d_in[1];   // (1, 1024)
    const float* W  = (const float*)d_in[2];   // (1, 10)
    const float* bv = (const float*)d_in[3];   // (10,)
    float* out      = (float*)d_out;           // (512, 10)
    hipLaunchKernelGGL(ssm_hippo_scan, dim3(512), dim3(64), 0, stream,
                       x, C, W, bv, out);
}